// Round 8
// baseline (132.986 us; speedup 1.0000x reference)
//
#include <hip/hip_runtime.h>
#include <math.h>

typedef float2 cplx;
__device__ __forceinline__ cplx mk(float r, float i){ return make_float2(r, i); }

// ---------------- state layout (identical to rounds 6/7) ----------------
// 1024-amp state per wave: 16 cplx regs x 64 lanes.
// state index n (10 bits): reg r = n[6:3]
// lane bits: n7->L0, n8->L1, n2->L2, n1->L3, n0->L4, n9->L5
template<int B> struct LSH {
  static constexpr int v = (B==7)?0 : (B==8)?1 : (B==2)?2 : (B==1)?3 : (B==0)?4 : 5;
};

template<int PB>
__device__ __forceinline__ float lx(float v){
  if constexpr (PB == 7)
    return __int_as_float(__builtin_amdgcn_update_dpp(
        __float_as_int(v), __float_as_int(v), 0xB1, 0xF, 0xF, false));
  else if constexpr (PB == 8)
    return __int_as_float(__builtin_amdgcn_update_dpp(
        __float_as_int(v), __float_as_int(v), 0x4E, 0xF, 0xF, false));
  else if constexpr (PB == 2)
    return __int_as_float(__builtin_amdgcn_ds_swizzle(__float_as_int(v), 0x101F));
  else if constexpr (PB == 1)
    return __int_as_float(__builtin_amdgcn_ds_swizzle(__float_as_int(v), 0x201F));
  else if constexpr (PB == 0)
    return __int_as_float(__builtin_amdgcn_ds_swizzle(__float_as_int(v), 0x401F));
  else
    return __shfl_xor(v, 32, 64);
}

template<int PB, int CB, bool ISRX>
__device__ __forceinline__ void gate_pass(cplx* A, float c, float s, int lane)
{
  if constexpr (PB >= 3 && PB <= 6) {
    constexpr int RM = 1 << (PB - 3);
    bool cl = false;
    if constexpr (CB >= 0 && !(CB >= 3 && CB <= 6))
      cl = (lane >> LSH<CB>::v) & 1;
    #pragma unroll
    for (int r = 0; r < 16; ++r) {
      if (r & RM) continue;
      cplx a0 = A[r], a1 = A[r | RM];
      bool sw;
      if constexpr (CB < 0) sw = false;
      else if constexpr (CB >= 3 && CB <= 6) sw = (r >> (CB - 3)) & 1;
      else sw = cl;
      float i0x = sw ? a1.x : a0.x, i0y = sw ? a1.y : a0.y;
      float i1x = sw ? a0.x : a1.x, i1y = sw ? a0.y : a1.y;
      if constexpr (ISRX) {
        A[r]      = mk(fmaf(s, i1y, c*i0x), fmaf(-s, i1x, c*i0y));
        A[r | RM] = mk(fmaf(s, i0y, c*i1x), fmaf(-s, i0x, c*i1y));
      } else {
        A[r]      = mk(fmaf(-s, i1x, c*i0x), fmaf(-s, i1y, c*i0y));
        A[r | RM] = mk(fmaf( s, i0x, c*i1x), fmaf( s, i0y, c*i1y));
      }
    }
  } else {
    const int mybit = (lane >> LSH<PB>::v) & 1;
    const float ssy = mybit ? s : -s;
    #pragma unroll
    for (int r = 0; r < 16; ++r) {
      float px = lx<PB>(A[r].x);
      float py = lx<PB>(A[r].y);
      bool sw = false;
      if constexpr (CB >= 3 && CB <= 6) sw = (r >> (CB - 3)) & 1;
      float ox = A[r].x, oy = A[r].y;
      float ux = sw ? px : ox, uy = sw ? py : oy;
      float vx = sw ? ox : px, vy = sw ? oy : py;
      if constexpr (ISRX) A[r] = mk(fmaf(s, vy, c*ux), fmaf(-s, vx, c*uy));
      else                A[r] = mk(fmaf(ssy, vx, c*ux), fmaf(ssy, vy, c*uy));
    }
  }
}

template<int LO>
__device__ __forceinline__ void iter_reg(cplx* A, int lane,
    float c0,float s0,float c1,float s1,float c2,float s2,
    float cx,float sx,float c4,float s4)
{
  gate_pass<LO+4, -1,   false>(A, c0, s0, lane);
  gate_pass<LO+1, LO+4, false>(A, c1, s1, lane);
  gate_pass<LO+3, -1,   false>(A, c2, s2, lane);
  gate_pass<LO,   LO+3, true >(A, cx, sx, lane);
  gate_pass<LO+3, LO+1, true >(A, c4, s4, lane);
}

#define RUN6_LOOP(A) \
  _Pragma("unroll 1") \
  for (int it = 0; it < niter; ++it){ \
    switch(it){ \
      case 0: iter_reg<5>(A,lane,hc0,hs0,hc1,hs1,hc2,hs2,hcx,hsx,hc4,hs4); break; \
      case 1: iter_reg<4>(A,lane,hc0,hs0,hc1,hs1,hc2,hs2,hcx,hsx,hc4,hs4); break; \
      case 2: iter_reg<3>(A,lane,hc0,hs0,hc1,hs1,hc2,hs2,hcx,hsx,hc4,hs4); break; \
      case 3: iter_reg<2>(A,lane,hc0,hs0,hc1,hs1,hc2,hs2,hcx,hsx,hc4,hs4); break; \
      case 4: iter_reg<1>(A,lane,hc0,hs0,hc1,hs1,hc2,hs2,hcx,hsx,hc4,hs4); break; \
      default: iter_reg<0>(A,lane,hc0,hs0,hc1,hs1,hc2,hs2,hcx,hsx,hc4,hs4); break; \
    } \
  }

// Producer: one wave per (b,k) pair. Computes angles + stage-1 Psi (wires 0..9),
// writes Psi (1024 cplx, indexed by state n) and angles to global; zeroes cnt.
__global__ __launch_bounds__(64) void stage1_kernel(
    const float* __restrict__ x, const float* __restrict__ kp,
    cplx* __restrict__ psi_g,   // (32,1024)
    float* __restrict__ cs_g,   // (32,32) cos/sin per wire
    unsigned* __restrict__ cnt, int niter)
{
  __shared__ float angw[32];
  const int lane = threadIdx.x;
  const int pair = blockIdx.x;
  const int b = pair & 15, k = pair >> 4;

  if (pair == 0 && lane == 0)
    __hip_atomic_store(cnt, 0u, __ATOMIC_RELAXED, __HIP_MEMORY_SCOPE_AGENT);

  // avgpool -> (cos,sin) half-angles
  {
    int a = lane >> 2, q = lane & 3;
    int ii = a >> 2, jj = a & 3;
    const float* xb = x + b*784 + ii*7*28 + jj*7;
    float s = 0.f;
    for (int e = q; e < 49; e += 4) s += xb[(e/7)*28 + (e%7)];
    s += __shfl_xor(s, 1, 64);
    s += __shfl_xor(s, 2, 64);
    float ang = s * (1.0f/49.0f) * 0.5f;
    if (q == 0){ angw[a*2] = cosf(ang); angw[a*2+1] = sinf(ang); }
  }

  const float* p5 = kp + k*5;
  float hc0 = cosf(p5[0]*0.5f), hs0 = sinf(p5[0]*0.5f);
  float hc1 = cosf(p5[1]*0.5f), hs1 = sinf(p5[1]*0.5f);
  float hc2 = cosf(p5[2]*0.5f), hs2 = sinf(p5[2]*0.5f);
  float hcx = cosf(p5[3]*0.5f), hsx = sinf(p5[3]*0.5f);
  float hc4 = cosf(p5[4]*0.5f), hs4 = sinf(p5[4]*0.5f);

  __threadfence_block();

  cplx A[16];
  // product state over wires 0..9 (wire w -> n bit 9-w)
  {
    float lp = 1.f;
    lp *= ((lane>>5)&1) ? angw[1]  : angw[0];
    lp *= ((lane>>1)&1) ? angw[3]  : angw[2];
    lp *= ( lane    &1) ? angw[5]  : angw[4];
    lp *= ((lane>>2)&1) ? angw[15] : angw[14];
    lp *= ((lane>>3)&1) ? angw[17] : angw[16];
    lp *= ((lane>>4)&1) ? angw[19] : angw[18];
    float c3 = angw[6],  s3 = angw[7];
    float c4w= angw[8],  s4w= angw[9];
    float c5 = angw[10], s5 = angw[11];
    float c6 = angw[12], s6 = angw[13];
    #pragma unroll
    for (int r = 0; r < 16; ++r){
      float rp = ((r&8)? s3:c3) * ((r&4)? s4w:c4w) * ((r&2)? s5:c5) * ((r&1)? s6:c6);
      A[r] = mk(lp * rp, 0.f);
    }
  }

  RUN6_LOOP(A);   // iterations 0..5

  // store Psi by state index n
  #pragma unroll
  for (int r = 0; r < 16; ++r){
    int n = (r << 3) | ((lane & 1) << 7) | (((lane >> 1) & 1) << 8)
          | (((lane >> 2) & 1) << 2) | (((lane >> 3) & 1) << 1)
          | ((lane >> 4) & 1) | (((lane >> 5) & 1) << 9);
    psi_g[pair*1024 + n] = A[r];
  }
  if (lane < 32) cs_g[pair*32 + lane] = angw[lane];
}

// Consumer: 512 blocks x 256 (2048 chunk-waves). Expand + stage 3 + measure.
// Last block reduces partials and runs the MLP.
__global__ __launch_bounds__(256) void stage3_kernel(
    const cplx* __restrict__ psi_g, const float* __restrict__ cs_g,
    const float* __restrict__ kp,
    float* __restrict__ pacc, unsigned* __restrict__ cnt,
    const float* __restrict__ w1, const float* __restrict__ b1,
    const float* __restrict__ w2, const float* __restrict__ b2,
    const float* __restrict__ w3, const float* __restrict__ b3,
    float* __restrict__ out, int niter)
{
  __shared__ float mlds[3456];   // winner: feats 384 | h1 2048 | h2 1024
  __shared__ int isLast;

  const int tid = threadIdx.x, wv = tid >> 6, lane = tid & 63;
  const int gw = blockIdx.x * 4 + wv;
  const int pair = gw >> 6;
  const int chunk = gw & 63;
  const int k = pair >> 4;

  const float* p5 = kp + k*5;
  float hc0 = cosf(p5[0]*0.5f), hs0 = sinf(p5[0]*0.5f);
  float hc1 = cosf(p5[1]*0.5f), hs1 = sinf(p5[1]*0.5f);
  float hc2 = cosf(p5[2]*0.5f), hs2 = sinf(p5[2]*0.5f);
  float hcx = cosf(p5[3]*0.5f), hsx = sinf(p5[3]*0.5f);
  float hc4 = cosf(p5[4]*0.5f), hs4 = sinf(p5[4]*0.5f);

  cplx A[16];
  {
    // gather this chunk's Psi window: 2 cplx per lane, one aligned float4
    int jc = (((lane>>5)&1) << 2) | (((lane>>1)&1) << 1) | (lane & 1);
    const float4 ld = *(const float4*)((const float*)psi_g
                        + (size_t)(pair*1024 + (chunk << 4) + (jc << 1)) * 2);
    cplx ps0 = mk(ld.x, ld.y), ps1 = mk(ld.z, ld.w);

    const float* cs = cs_g + pair*32;
    float c10 = cs[20], s10 = cs[21];
    float c11 = cs[22], s11 = cs[23];
    float c12 = cs[24], s12 = cs[25];
    float preL = 1.f;
    preL *= ((lane>>2)&1) ? cs[27] : cs[26];  // wire13
    preL *= ((lane>>3)&1) ? cs[29] : cs[28];  // wire14
    preL *= ((lane>>4)&1) ? cs[31] : cs[30];  // wire15
    #pragma unroll
    for (int r = 0; r < 16; ++r){
      float f = preL * (((r&4)? s10:c10) * ((r&2)? s11:c11) * ((r&1)? s12:c12));
      cplx v = (r & 8) ? ps1 : ps0;
      A[r] = mk(v.x * f, v.y * f);
    }
  }

  RUN6_LOOP(A);   // iterations 6..11

  // measurement: E[Z_w], final CNOT block folded into parity masks
  {
    int idx_hi = (chunk << 10)
      | (((lane>>5)&1) << 9) | (((lane>>1)&1) << 8) | ((lane & 1) << 7)
      | (((lane>>2)&1) << 2) | (((lane>>3)&1) << 1) | ((lane>>4)&1);
    float p[16];
    #pragma unroll
    for (int r = 0; r < 16; ++r) p[r] = A[r].x*A[r].x + A[r].y*A[r].y;
    #pragma unroll 1
    for (int w = 0; w < 12; ++w){
      int m = 27 << (11 - w);
      float s = 0.f;
      #pragma unroll
      for (int r = 0; r < 16; ++r)
        s += (__popc((r << 3) & m) & 1) ? -p[r] : p[r];
      s = (__popc(idx_hi & m) & 1) ? -s : s;
      s += lx<7>(s);
      s += lx<8>(s);
      s += lx<2>(s);
      s += lx<1>(s);
      s += lx<0>(s);
      s += __shfl_xor(s, 32, 64);
      if (lane == 0)
        __hip_atomic_store(&pacc[gw*12 + w], s, __ATOMIC_RELAXED, __HIP_MEMORY_SCOPE_AGENT);
    }
  }

  // last-block election (round-5-proven pattern)
  __syncthreads();
  if (tid == 0){
    __threadfence();
    unsigned old = __hip_atomic_fetch_add(cnt, 1u, __ATOMIC_ACQ_REL, __HIP_MEMORY_SCOPE_AGENT);
    isLast = (old == 511u);
  }
  __syncthreads();
  if (!isLast) return;
  __threadfence();

  // winner: reduce pacc over 64 chunks per pair, then MLP
  float* feats = mlds;          // 16*24
  float* h1    = mlds + 384;    // 16*128
  float* h2    = mlds + 2432;   // 16*64
  {
    int pr = tid >> 3, part = tid & 7;   // pr = pair (k*16+b)
    float sm[12];
    #pragma unroll
    for (int w = 0; w < 12; ++w) sm[w] = 0.f;
    for (int c = part; c < 64; c += 8){
      const float* row = pacc + (pr*64 + c)*12;
      #pragma unroll
      for (int w = 0; w < 12; ++w)
        sm[w] += __hip_atomic_load(&row[w], __ATOMIC_RELAXED, __HIP_MEMORY_SCOPE_AGENT);
    }
    #pragma unroll
    for (int m = 1; m < 8; m <<= 1)
      #pragma unroll
      for (int w = 0; w < 12; ++w)
        sm[w] += __shfl_xor(sm[w], m, 64);
    if (part == 0){
      int bb = pr & 15, kk = pr >> 4;
      #pragma unroll
      for (int w = 0; w < 12; ++w)
        feats[bb*24 + kk*12 + w] = sm[w];
    }
  }
  __syncthreads();

  for (int e = tid; e < 2048; e += 256){
    int bb = e >> 7, j = e & 127;
    const float4* wr = (const float4*)(w1 + j*24);
    const float4* fr = (const float4*)(feats + bb*24);
    float s = b1[j];
    #pragma unroll
    for (int q = 0; q < 6; ++q){
      float4 a = fr[q], w4 = wr[q];
      s += a.x*w4.x + a.y*w4.y + a.z*w4.z + a.w*w4.w;
    }
    h1[e] = fmaxf(s, 0.f);
  }
  __syncthreads();
  for (int e = tid; e < 1024; e += 256){
    int bb = e >> 6, j = e & 63;
    const float4* wr = (const float4*)(w2 + j*128);
    const float4* hr = (const float4*)(h1 + bb*128);
    float s = b2[j];
    #pragma unroll
    for (int q = 0; q < 32; ++q){
      float4 a = hr[q], w4 = wr[q];
      s += a.x*w4.x + a.y*w4.y + a.z*w4.z + a.w*w4.w;
    }
    h2[e] = fmaxf(s, 0.f);
  }
  __syncthreads();
  if (tid < 64){
    int bb = tid >> 2, j = tid & 3;
    const float4* wr = (const float4*)(w3 + j*64);
    const float4* hr = (const float4*)(h2 + bb*64);
    float s = b3[j];
    #pragma unroll
    for (int q = 0; q < 16; ++q){
      float4 a = hr[q], w4 = wr[q];
      s += a.x*w4.x + a.y*w4.y + a.z*w4.z + a.w*w4.w;
    }
    out[tid] = s;
  }
}

extern "C" void kernel_launch(void* const* d_in, const int* in_sizes, int n_in,
                              void* d_out, int out_size, void* d_ws, size_t ws_size,
                              hipStream_t stream) {
  const float* x  = (const float*)d_in[0];
  const float* kp = (const float*)d_in[1];
  const float* w1 = (const float*)d_in[2];
  const float* b1 = (const float*)d_in[3];
  const float* w2 = (const float*)d_in[4];
  const float* b2 = (const float*)d_in[5];
  const float* w3 = (const float*)d_in[6];
  const float* b3 = (const float*)d_in[7];
  float* out = (float*)d_out;

  char* ws = (char*)d_ws;
  cplx*     psi_g = (cplx*)ws;                      // 32*1024*8   = 262144 B
  float*    cs_g  = (float*)(ws + 262144);          // 32*32*4     = 4096 B
  float*    pacc  = (float*)(ws + 266240);          // 2048*12*4   = 98304 B
  unsigned* cnt   = (unsigned*)(ws + 364544);       // 4 B

  stage1_kernel<<<32, 64, 0, stream>>>(x, kp, psi_g, cs_g, cnt, 6);
  stage3_kernel<<<512, 256, 0, stream>>>(psi_g, cs_g, kp, pacc, cnt,
                                         w1, b1, w2, b2, w3, b3, out, 6);
}

// Round 9
// 108.575 us; speedup vs baseline: 1.2248x; 1.2248x over previous
//
#include <hip/hip_runtime.h>
#include <math.h>

typedef float v2f __attribute__((ext_vector_type(2)));
__device__ __forceinline__ v2f sp(float f){ return (v2f){f, f}; }
__device__ __forceinline__ v2f Jv(v2f v){ return (v2f){v.y, -v.x}; }  // -i * v

// ---------------- state layout (identical to rounds 6-8) ----------------
// 1024-amp state per wave: 16 cplx regs x 64 lanes.
// state index n (10 bits): reg r = n[6:3]
// lane bits: n7->L0, n8->L1, n2->L2, n1->L3, n0->L4, n9->L5
template<int B> struct LSH {
  static constexpr int v = (B==7)?0 : (B==8)?1 : (B==2)?2 : (B==1)?3 : (B==0)?4 : 5;
};

template<int PB>
__device__ __forceinline__ float lx(float v){
  if constexpr (PB == 7)
    return __int_as_float(__builtin_amdgcn_update_dpp(
        __float_as_int(v), __float_as_int(v), 0xB1, 0xF, 0xF, false));
  else if constexpr (PB == 8)
    return __int_as_float(__builtin_amdgcn_update_dpp(
        __float_as_int(v), __float_as_int(v), 0x4E, 0xF, 0xF, false));
  else if constexpr (PB == 2)
    return __int_as_float(__builtin_amdgcn_ds_swizzle(__float_as_int(v), 0x101F));
  else if constexpr (PB == 1)
    return __int_as_float(__builtin_amdgcn_ds_swizzle(__float_as_int(v), 0x201F));
  else if constexpr (PB == 0)
    return __int_as_float(__builtin_amdgcn_ds_swizzle(__float_as_int(v), 0x401F));
  else
    return __shfl_xor(v, 32, 64);
}

// Rotation pairing amplitudes across state bit PB, optional CNOT control on
// state bit CB (control=1 => inputs swapped). Packed fp32 (v_pk_fma_f32) math.
template<int PB, int CB, bool ISRX>
__device__ __forceinline__ void gate_pass(v2f* A, float c, float s, int lane)
{
  const v2f vc = sp(c), vs = sp(s);
  if constexpr (PB >= 3 && PB <= 6) {
    constexpr int RM = 1 << (PB - 3);
    bool cl = false;
    if constexpr (CB >= 0 && !(CB >= 3 && CB <= 6))
      cl = (lane >> LSH<CB>::v) & 1;
    #pragma unroll
    for (int r = 0; r < 16; ++r) {
      if (r & RM) continue;
      v2f a0 = A[r], a1 = A[r | RM];
      bool sw;
      if constexpr (CB < 0) sw = false;
      else if constexpr (CB >= 3 && CB <= 6) sw = (r >> (CB - 3)) & 1;
      else sw = cl;
      v2f i0 = sw ? a1 : a0;
      v2f i1 = sw ? a0 : a1;
      if constexpr (ISRX) {
        A[r]      = __builtin_elementwise_fma(Jv(i1), vs, i0 * vc);
        A[r | RM] = __builtin_elementwise_fma(Jv(i0), vs, i1 * vc);
      } else {
        A[r]      = __builtin_elementwise_fma(i1, -vs, i0 * vc);
        A[r | RM] = __builtin_elementwise_fma(i0,  vs, i1 * vc);
      }
    }
  } else {
    const int mybit = (lane >> LSH<PB>::v) & 1;
    const v2f vssy = sp(mybit ? s : -s);
    #pragma unroll
    for (int r = 0; r < 16; ++r) {
      v2f p = (v2f){ lx<PB>(A[r].x), lx<PB>(A[r].y) };
      bool sw = false;
      if constexpr (CB >= 3 && CB <= 6) sw = (r >> (CB - 3)) & 1;
      v2f o = A[r];
      v2f u = sw ? p : o;
      v2f v = sw ? o : p;
      if constexpr (ISRX) A[r] = __builtin_elementwise_fma(Jv(v), vs, u * vc);
      else                A[r] = __builtin_elementwise_fma(v, vssy, u * vc);
    }
  }
}

template<int LO>
__device__ __forceinline__ void iter_reg(v2f* A, int lane,
    float c0,float s0,float c1,float s1,float c2,float s2,
    float cx,float sx,float c4,float s4)
{
  gate_pass<LO+4, -1,   false>(A, c0, s0, lane);
  gate_pass<LO+1, LO+4, false>(A, c1, s1, lane);
  gate_pass<LO+3, -1,   false>(A, c2, s2, lane);
  gate_pass<LO,   LO+3, true >(A, cx, sx, lane);
  gate_pass<LO+3, LO+1, true >(A, c4, s4, lane);
}

#define RUN6_LOOP(A) \
  _Pragma("unroll 1") \
  for (int it = 0; it < niter; ++it){ \
    switch(it){ \
      case 0: iter_reg<5>(A,lane,hc0,hs0,hc1,hs1,hc2,hs2,hcx,hsx,hc4,hs4); break; \
      case 1: iter_reg<4>(A,lane,hc0,hs0,hc1,hs1,hc2,hs2,hcx,hsx,hc4,hs4); break; \
      case 2: iter_reg<3>(A,lane,hc0,hs0,hc1,hs1,hc2,hs2,hcx,hsx,hc4,hs4); break; \
      case 3: iter_reg<2>(A,lane,hc0,hs0,hc1,hs1,hc2,hs2,hcx,hsx,hc4,hs4); break; \
      case 4: iter_reg<1>(A,lane,hc0,hs0,hc1,hs1,hc2,hs2,hcx,hsx,hc4,hs4); break; \
      default: iter_reg<0>(A,lane,hc0,hs0,hc1,hs1,hc2,hs2,hcx,hsx,hc4,hs4); break; \
    } \
  }

// Producer: one wave per (b,k) pair. angles + stage-1 Psi (wires 0..9) -> global.
__global__ __launch_bounds__(64) void stage1_kernel(
    const float* __restrict__ x, const float* __restrict__ kp,
    v2f* __restrict__ psi_g,    // (32,1024)
    float* __restrict__ cs_g,   // (32,32)
    int niter)
{
  __shared__ float angw[32];
  const int lane = threadIdx.x;
  const int pair = blockIdx.x;
  const int b = pair & 15, k = pair >> 4;

  {
    int a = lane >> 2, q = lane & 3;
    int ii = a >> 2, jj = a & 3;
    const float* xb = x + b*784 + ii*7*28 + jj*7;
    float s = 0.f;
    for (int e = q; e < 49; e += 4) s += xb[(e/7)*28 + (e%7)];
    s += __shfl_xor(s, 1, 64);
    s += __shfl_xor(s, 2, 64);
    float ang = s * (1.0f/49.0f) * 0.5f;
    if (q == 0){ angw[a*2] = cosf(ang); angw[a*2+1] = sinf(ang); }
  }

  const float* p5 = kp + k*5;
  float hc0 = cosf(p5[0]*0.5f), hs0 = sinf(p5[0]*0.5f);
  float hc1 = cosf(p5[1]*0.5f), hs1 = sinf(p5[1]*0.5f);
  float hc2 = cosf(p5[2]*0.5f), hs2 = sinf(p5[2]*0.5f);
  float hcx = cosf(p5[3]*0.5f), hsx = sinf(p5[3]*0.5f);
  float hc4 = cosf(p5[4]*0.5f), hs4 = sinf(p5[4]*0.5f);

  __threadfence_block();

  v2f A[16];
  {
    float lp = 1.f;
    lp *= ((lane>>5)&1) ? angw[1]  : angw[0];
    lp *= ((lane>>1)&1) ? angw[3]  : angw[2];
    lp *= ( lane    &1) ? angw[5]  : angw[4];
    lp *= ((lane>>2)&1) ? angw[15] : angw[14];
    lp *= ((lane>>3)&1) ? angw[17] : angw[16];
    lp *= ((lane>>4)&1) ? angw[19] : angw[18];
    float c3 = angw[6],  s3 = angw[7];
    float c4w= angw[8],  s4w= angw[9];
    float c5 = angw[10], s5 = angw[11];
    float c6 = angw[12], s6 = angw[13];
    #pragma unroll
    for (int r = 0; r < 16; ++r){
      float rp = ((r&8)? s3:c3) * ((r&4)? s4w:c4w) * ((r&2)? s5:c5) * ((r&1)? s6:c6);
      A[r] = (v2f){lp * rp, 0.f};
    }
  }

  RUN6_LOOP(A);   // iterations 0..5

  #pragma unroll
  for (int r = 0; r < 16; ++r){
    int n = (r << 3) | ((lane & 1) << 7) | (((lane >> 1) & 1) << 8)
          | (((lane >> 2) & 1) << 2) | (((lane >> 3) & 1) << 1)
          | ((lane >> 4) & 1) | (((lane >> 5) & 1) << 9);
    psi_g[pair*1024 + n] = A[r];
  }
  if (lane < 32) cs_g[pair*32 + lane] = angw[lane];
}

// Consumer: 512 blocks x 256 (2048 chunk-waves). Expand + stage 3 + measure.
__global__ __launch_bounds__(256) void stage3_kernel(
    const v2f* __restrict__ psi_g, const float* __restrict__ cs_g,
    const float* __restrict__ kp, float* __restrict__ pacc, int niter)
{
  const int tid = threadIdx.x, wv = tid >> 6, lane = tid & 63;
  const int gw = blockIdx.x * 4 + wv;
  const int pair = gw >> 6;
  const int chunk = gw & 63;
  const int k = pair >> 4;

  const float* p5 = kp + k*5;
  float hc0 = cosf(p5[0]*0.5f), hs0 = sinf(p5[0]*0.5f);
  float hc1 = cosf(p5[1]*0.5f), hs1 = sinf(p5[1]*0.5f);
  float hc2 = cosf(p5[2]*0.5f), hs2 = sinf(p5[2]*0.5f);
  float hcx = cosf(p5[3]*0.5f), hsx = sinf(p5[3]*0.5f);
  float hc4 = cosf(p5[4]*0.5f), hs4 = sinf(p5[4]*0.5f);

  v2f A[16];
  {
    int jc = (((lane>>5)&1) << 2) | (((lane>>1)&1) << 1) | (lane & 1);
    const float4 ld = *(const float4*)((const float*)psi_g
                        + (size_t)(pair*1024 + (chunk << 4) + (jc << 1)) * 2);
    v2f ps0 = (v2f){ld.x, ld.y}, ps1 = (v2f){ld.z, ld.w};

    const float* cs = cs_g + pair*32;
    float c10 = cs[20], s10 = cs[21];
    float c11 = cs[22], s11 = cs[23];
    float c12 = cs[24], s12 = cs[25];
    float preL = 1.f;
    preL *= ((lane>>2)&1) ? cs[27] : cs[26];  // wire13
    preL *= ((lane>>3)&1) ? cs[29] : cs[28];  // wire14
    preL *= ((lane>>4)&1) ? cs[31] : cs[30];  // wire15
    #pragma unroll
    for (int r = 0; r < 16; ++r){
      float f = preL * (((r&4)? s10:c10) * ((r&2)? s11:c11) * ((r&1)? s12:c12));
      A[r] = ((r & 8) ? ps1 : ps0) * sp(f);
    }
  }

  RUN6_LOOP(A);   // iterations 6..11

  // measurement: E[Z_w], final CNOT block folded into parity masks
  {
    int idx_hi = (chunk << 10)
      | (((lane>>5)&1) << 9) | (((lane>>1)&1) << 8) | ((lane & 1) << 7)
      | (((lane>>2)&1) << 2) | (((lane>>3)&1) << 1) | ((lane>>4)&1);
    float p[16];
    #pragma unroll
    for (int r = 0; r < 16; ++r) p[r] = A[r].x*A[r].x + A[r].y*A[r].y;
    #pragma unroll 1
    for (int w = 0; w < 12; ++w){
      int m = 27 << (11 - w);
      float s = 0.f;
      #pragma unroll
      for (int r = 0; r < 16; ++r)
        s += (__popc((r << 3) & m) & 1) ? -p[r] : p[r];
      s = (__popc(idx_hi & m) & 1) ? -s : s;
      s += lx<7>(s);
      s += lx<8>(s);
      s += lx<2>(s);
      s += lx<1>(s);
      s += lx<0>(s);
      s += __shfl_xor(s, 32, 64);
      if (lane == 0) pacc[gw*12 + w] = s;
    }
  }
}

__global__ __launch_bounds__(256) void mlp_kernel(
    const float* __restrict__ pacc,
    const float* __restrict__ w1, const float* __restrict__ b1,
    const float* __restrict__ w2, const float* __restrict__ b2,
    const float* __restrict__ w3, const float* __restrict__ b3,
    float* __restrict__ out)
{
  __shared__ float feats[16*24];
  __shared__ float h1[16*128];
  __shared__ float h2[16*64];
  int tid = threadIdx.x;

  {
    int pr = tid >> 3, part = tid & 7;   // pr = pair (k*16+b)
    float sm[12];
    #pragma unroll
    for (int w = 0; w < 12; ++w) sm[w] = 0.f;
    for (int c = part; c < 64; c += 8){
      const float4* row = (const float4*)(pacc + (pr*64 + c)*12);
      float4 r0 = row[0], r1 = row[1], r2 = row[2];
      sm[0]+=r0.x; sm[1]+=r0.y; sm[2] +=r0.z; sm[3] +=r0.w;
      sm[4]+=r1.x; sm[5]+=r1.y; sm[6] +=r1.z; sm[7] +=r1.w;
      sm[8]+=r2.x; sm[9]+=r2.y; sm[10]+=r2.z; sm[11]+=r2.w;
    }
    #pragma unroll
    for (int m = 1; m < 8; m <<= 1)
      #pragma unroll
      for (int w = 0; w < 12; ++w)
        sm[w] += __shfl_xor(sm[w], m, 64);
    if (part == 0){
      int bb = pr & 15, kk = pr >> 4;
      #pragma unroll
      for (int w = 0; w < 12; ++w)
        feats[bb*24 + kk*12 + w] = sm[w];
    }
  }
  __syncthreads();

  for (int e = tid; e < 2048; e += 256){
    int bb = e >> 7, j = e & 127;
    const float4* wr = (const float4*)(w1 + j*24);
    const float4* fr = (const float4*)(feats + bb*24);
    float s = b1[j];
    #pragma unroll
    for (int q = 0; q < 6; ++q){
      float4 a = fr[q], w4 = wr[q];
      s += a.x*w4.x + a.y*w4.y + a.z*w4.z + a.w*w4.w;
    }
    h1[e] = fmaxf(s, 0.f);
  }
  __syncthreads();
  for (int e = tid; e < 1024; e += 256){
    int bb = e >> 6, j = e & 63;
    const float4* wr = (const float4*)(w2 + j*128);
    const float4* hr = (const float4*)(h1 + bb*128);
    float s = b2[j];
    #pragma unroll
    for (int q = 0; q < 32; ++q){
      float4 a = hr[q], w4 = wr[q];
      s += a.x*w4.x + a.y*w4.y + a.z*w4.z + a.w*w4.w;
    }
    h2[e] = fmaxf(s, 0.f);
  }
  __syncthreads();
  if (tid < 64){
    int bb = tid >> 2, j = tid & 3;
    const float4* wr = (const float4*)(w3 + j*64);
    const float4* hr = (const float4*)(h2 + bb*64);
    float s = b3[j];
    #pragma unroll
    for (int q = 0; q < 16; ++q){
      float4 a = hr[q], w4 = wr[q];
      s += a.x*w4.x + a.y*w4.y + a.z*w4.z + a.w*w4.w;
    }
    out[tid] = s;
  }
}

extern "C" void kernel_launch(void* const* d_in, const int* in_sizes, int n_in,
                              void* d_out, int out_size, void* d_ws, size_t ws_size,
                              hipStream_t stream) {
  const float* x  = (const float*)d_in[0];
  const float* kp = (const float*)d_in[1];
  const float* w1 = (const float*)d_in[2];
  const float* b1 = (const float*)d_in[3];
  const float* w2 = (const float*)d_in[4];
  const float* b2 = (const float*)d_in[5];
  const float* w3 = (const float*)d_in[6];
  const float* b3 = (const float*)d_in[7];
  float* out = (float*)d_out;

  char* ws = (char*)d_ws;
  v2f*   psi_g = (v2f*)ws;                  // 32*1024*8 = 262144 B
  float* cs_g  = (float*)(ws + 262144);     // 32*32*4   = 4096 B
  float* pacc  = (float*)(ws + 266240);     // 2048*12*4 = 98304 B

  stage1_kernel<<<32, 64, 0, stream>>>(x, kp, psi_g, cs_g, 6);
  stage3_kernel<<<512, 256, 0, stream>>>(psi_g, cs_g, kp, pacc, 6);
  mlp_kernel<<<1, 256, 0, stream>>>(pacc, w1, b1, w2, b2, w3, b3, out);
}

// Round 10
// 105.405 us; speedup vs baseline: 1.2617x; 1.0301x over previous
//
#include <hip/hip_runtime.h>
#include <math.h>

typedef float2 cplx;
__device__ __forceinline__ cplx mk(float r, float i){ return make_float2(r, i); }

// ---------------- state layout (identical to rounds 6-9) ----------------
// 1024-amp state per wave: 16 cplx regs x 64 lanes.
// state index n (10 bits): reg r = n[6:3]
// lane bits: n7->L0, n8->L1, n2->L2, n1->L3, n0->L4, n9->L5
template<int B> struct LSH {
  static constexpr int v = (B==7)?0 : (B==8)?1 : (B==2)?2 : (B==1)?3 : (B==0)?4 : 5;
};

template<int PB>
__device__ __forceinline__ float lx(float v){
  if constexpr (PB == 7)
    return __int_as_float(__builtin_amdgcn_update_dpp(
        __float_as_int(v), __float_as_int(v), 0xB1, 0xF, 0xF, false));
  else if constexpr (PB == 8)
    return __int_as_float(__builtin_amdgcn_update_dpp(
        __float_as_int(v), __float_as_int(v), 0x4E, 0xF, 0xF, false));
  else if constexpr (PB == 2)
    return __int_as_float(__builtin_amdgcn_ds_swizzle(__float_as_int(v), 0x101F));
  else if constexpr (PB == 1)
    return __int_as_float(__builtin_amdgcn_ds_swizzle(__float_as_int(v), 0x201F));
  else if constexpr (PB == 0)
    return __int_as_float(__builtin_amdgcn_ds_swizzle(__float_as_int(v), 0x401F));
  else
    return __shfl_xor(v, 32, 64);
}

// Scalar-cplx gate pass (round 6/7 proven-fast version).
template<int PB, int CB, bool ISRX>
__device__ __forceinline__ void gate_pass(cplx* A, float c, float s, int lane)
{
  if constexpr (PB >= 3 && PB <= 6) {
    constexpr int RM = 1 << (PB - 3);
    bool cl = false;
    if constexpr (CB >= 0 && !(CB >= 3 && CB <= 6))
      cl = (lane >> LSH<CB>::v) & 1;
    #pragma unroll
    for (int r = 0; r < 16; ++r) {
      if (r & RM) continue;
      cplx a0 = A[r], a1 = A[r | RM];
      bool sw;
      if constexpr (CB < 0) sw = false;
      else if constexpr (CB >= 3 && CB <= 6) sw = (r >> (CB - 3)) & 1;
      else sw = cl;
      float i0x = sw ? a1.x : a0.x, i0y = sw ? a1.y : a0.y;
      float i1x = sw ? a0.x : a1.x, i1y = sw ? a0.y : a1.y;
      if constexpr (ISRX) {
        A[r]      = mk(fmaf(s, i1y, c*i0x), fmaf(-s, i1x, c*i0y));
        A[r | RM] = mk(fmaf(s, i0y, c*i1x), fmaf(-s, i0x, c*i1y));
      } else {
        A[r]      = mk(fmaf(-s, i1x, c*i0x), fmaf(-s, i1y, c*i0y));
        A[r | RM] = mk(fmaf( s, i0x, c*i1x), fmaf( s, i0y, c*i1y));
      }
    }
  } else {
    const int mybit = (lane >> LSH<PB>::v) & 1;
    const float ssy = mybit ? s : -s;
    #pragma unroll
    for (int r = 0; r < 16; ++r) {
      float px = lx<PB>(A[r].x);
      float py = lx<PB>(A[r].y);
      bool sw = false;
      if constexpr (CB >= 3 && CB <= 6) sw = (r >> (CB - 3)) & 1;
      float ox = A[r].x, oy = A[r].y;
      float ux = sw ? px : ox, uy = sw ? py : oy;
      float vx = sw ? ox : px, vy = sw ? oy : py;
      if constexpr (ISRX) A[r] = mk(fmaf(s, vy, c*ux), fmaf(-s, vx, c*uy));
      else                A[r] = mk(fmaf(ssy, vx, c*ux), fmaf(ssy, vy, c*uy));
    }
  }
}

template<int LO>
__device__ __forceinline__ void iter_reg(cplx* A, int lane,
    float c0,float s0,float c1,float s1,float c2,float s2,
    float cx,float sx,float c4,float s4)
{
  gate_pass<LO+4, -1,   false>(A, c0, s0, lane);
  gate_pass<LO+1, LO+4, false>(A, c1, s1, lane);
  gate_pass<LO+3, -1,   false>(A, c2, s2, lane);
  gate_pass<LO,   LO+3, true >(A, cx, sx, lane);
  gate_pass<LO+3, LO+1, true >(A, c4, s4, lane);
}

#define RUN6_LOOP(A) \
  _Pragma("unroll 1") \
  for (int it = 0; it < niter; ++it){ \
    switch(it){ \
      case 0: iter_reg<5>(A,lane,hc0,hs0,hc1,hs1,hc2,hs2,hcx,hsx,hc4,hs4); break; \
      case 1: iter_reg<4>(A,lane,hc0,hs0,hc1,hs1,hc2,hs2,hcx,hsx,hc4,hs4); break; \
      case 2: iter_reg<3>(A,lane,hc0,hs0,hc1,hs1,hc2,hs2,hcx,hsx,hc4,hs4); break; \
      case 3: iter_reg<2>(A,lane,hc0,hs0,hc1,hs1,hc2,hs2,hcx,hsx,hc4,hs4); break; \
      case 4: iter_reg<1>(A,lane,hc0,hs0,hc1,hs1,hc2,hs2,hcx,hsx,hc4,hs4); break; \
      default: iter_reg<0>(A,lane,hc0,hs0,hc1,hs1,hc2,hs2,hcx,hsx,hc4,hs4); break; \
    } \
  }

// Producer: one wave per (b,k) pair. angles + stage-1 Psi (wires 0..9) -> global.
__global__ __launch_bounds__(64) void stage1_kernel(
    const float* __restrict__ x, const float* __restrict__ kp,
    cplx* __restrict__ psi_g,   // (32,1024)
    float* __restrict__ cs_g,   // (32,32)
    int niter)
{
  __shared__ float angw[32];
  const int lane = threadIdx.x;
  const int pair = blockIdx.x;
  const int b = pair & 15, k = pair >> 4;

  {
    int a = lane >> 2, q = lane & 3;
    int ii = a >> 2, jj = a & 3;
    const float* xb = x + b*784 + ii*7*28 + jj*7;
    float s = 0.f;
    for (int e = q; e < 49; e += 4) s += xb[(e/7)*28 + (e%7)];
    s += __shfl_xor(s, 1, 64);
    s += __shfl_xor(s, 2, 64);
    float ang = s * (1.0f/49.0f) * 0.5f;
    if (q == 0){ angw[a*2] = cosf(ang); angw[a*2+1] = sinf(ang); }
  }

  const float* p5 = kp + k*5;
  float hc0 = cosf(p5[0]*0.5f), hs0 = sinf(p5[0]*0.5f);
  float hc1 = cosf(p5[1]*0.5f), hs1 = sinf(p5[1]*0.5f);
  float hc2 = cosf(p5[2]*0.5f), hs2 = sinf(p5[2]*0.5f);
  float hcx = cosf(p5[3]*0.5f), hsx = sinf(p5[3]*0.5f);
  float hc4 = cosf(p5[4]*0.5f), hs4 = sinf(p5[4]*0.5f);

  __threadfence_block();

  cplx A[16];
  {
    float lp = 1.f;
    lp *= ((lane>>5)&1) ? angw[1]  : angw[0];
    lp *= ((lane>>1)&1) ? angw[3]  : angw[2];
    lp *= ( lane    &1) ? angw[5]  : angw[4];
    lp *= ((lane>>2)&1) ? angw[15] : angw[14];
    lp *= ((lane>>3)&1) ? angw[17] : angw[16];
    lp *= ((lane>>4)&1) ? angw[19] : angw[18];
    float c3 = angw[6],  s3 = angw[7];
    float c4w= angw[8],  s4w= angw[9];
    float c5 = angw[10], s5 = angw[11];
    float c6 = angw[12], s6 = angw[13];
    #pragma unroll
    for (int r = 0; r < 16; ++r){
      float rp = ((r&8)? s3:c3) * ((r&4)? s4w:c4w) * ((r&2)? s5:c5) * ((r&1)? s6:c6);
      A[r] = mk(lp * rp, 0.f);
    }
  }

  RUN6_LOOP(A);   // iterations 0..5

  #pragma unroll
  for (int r = 0; r < 16; ++r){
    int n = (r << 3) | ((lane & 1) << 7) | (((lane >> 1) & 1) << 8)
          | (((lane >> 2) & 1) << 2) | (((lane >> 3) & 1) << 1)
          | ((lane >> 4) & 1) | (((lane >> 5) & 1) << 9);
    psi_g[pair*1024 + n] = A[r];
  }
  if (lane < 32) cs_g[pair*32 + lane] = angw[lane];
}

// Consumer: 512 blocks x 256 (2048 chunk-waves). Expand + stage 3 + measure.
__global__ __launch_bounds__(256) void stage3_kernel(
    const cplx* __restrict__ psi_g, const float* __restrict__ cs_g,
    const float* __restrict__ kp, float* __restrict__ pacc, int niter)
{
  const int tid = threadIdx.x, wv = tid >> 6, lane = tid & 63;
  const int gw = blockIdx.x * 4 + wv;
  const int pair = gw >> 6;
  const int chunk = gw & 63;
  const int k = pair >> 4;

  const float* p5 = kp + k*5;
  float hc0 = cosf(p5[0]*0.5f), hs0 = sinf(p5[0]*0.5f);
  float hc1 = cosf(p5[1]*0.5f), hs1 = sinf(p5[1]*0.5f);
  float hc2 = cosf(p5[2]*0.5f), hs2 = sinf(p5[2]*0.5f);
  float hcx = cosf(p5[3]*0.5f), hsx = sinf(p5[3]*0.5f);
  float hc4 = cosf(p5[4]*0.5f), hs4 = sinf(p5[4]*0.5f);

  cplx A[16];
  {
    int jc = (((lane>>5)&1) << 2) | (((lane>>1)&1) << 1) | (lane & 1);
    const float4 ld = *(const float4*)((const float*)psi_g
                        + (size_t)(pair*1024 + (chunk << 4) + (jc << 1)) * 2);
    cplx ps0 = mk(ld.x, ld.y), ps1 = mk(ld.z, ld.w);

    const float* cs = cs_g + pair*32;
    float c10 = cs[20], s10 = cs[21];
    float c11 = cs[22], s11 = cs[23];
    float c12 = cs[24], s12 = cs[25];
    float preL = 1.f;
    preL *= ((lane>>2)&1) ? cs[27] : cs[26];  // wire13
    preL *= ((lane>>3)&1) ? cs[29] : cs[28];  // wire14
    preL *= ((lane>>4)&1) ? cs[31] : cs[30];  // wire15
    #pragma unroll
    for (int r = 0; r < 16; ++r){
      float f = preL * (((r&4)? s10:c10) * ((r&2)? s11:c11) * ((r&1)? s12:c12));
      cplx v = (r & 8) ? ps1 : ps0;
      A[r] = mk(v.x * f, v.y * f);
    }
  }

  RUN6_LOOP(A);   // iterations 6..11

  // measurement: E[Z_w], final CNOT block folded into parity masks
  {
    int idx_hi = (chunk << 10)
      | (((lane>>5)&1) << 9) | (((lane>>1)&1) << 8) | ((lane & 1) << 7)
      | (((lane>>2)&1) << 2) | (((lane>>3)&1) << 1) | ((lane>>4)&1);
    float p[16];
    #pragma unroll
    for (int r = 0; r < 16; ++r) p[r] = A[r].x*A[r].x + A[r].y*A[r].y;
    #pragma unroll 1
    for (int w = 0; w < 12; ++w){
      int m = 27 << (11 - w);
      float s = 0.f;
      #pragma unroll
      for (int r = 0; r < 16; ++r)
        s += (__popc((r << 3) & m) & 1) ? -p[r] : p[r];
      s = (__popc(idx_hi & m) & 1) ? -s : s;
      s += lx<7>(s);
      s += lx<8>(s);
      s += lx<2>(s);
      s += lx<1>(s);
      s += lx<0>(s);
      s += __shfl_xor(s, 32, 64);
      if (lane == 0) pacc[gw*12 + w] = s;
    }
  }
}

__global__ __launch_bounds__(256) void mlp_kernel(
    const float* __restrict__ pacc,
    const float* __restrict__ w1, const float* __restrict__ b1,
    const float* __restrict__ w2, const float* __restrict__ b2,
    const float* __restrict__ w3, const float* __restrict__ b3,
    float* __restrict__ out)
{
  __shared__ float feats[16*24];
  __shared__ float h1[16*128];
  __shared__ float h2[16*64];
  int tid = threadIdx.x;

  {
    int pr = tid >> 3, part = tid & 7;   // pr = pair (k*16+b)
    float sm[12];
    #pragma unroll
    for (int w = 0; w < 12; ++w) sm[w] = 0.f;
    for (int c = part; c < 64; c += 8){
      const float4* row = (const float4*)(pacc + (pr*64 + c)*12);
      float4 r0 = row[0], r1 = row[1], r2 = row[2];
      sm[0]+=r0.x; sm[1]+=r0.y; sm[2] +=r0.z; sm[3] +=r0.w;
      sm[4]+=r1.x; sm[5]+=r1.y; sm[6] +=r1.z; sm[7] +=r1.w;
      sm[8]+=r2.x; sm[9]+=r2.y; sm[10]+=r2.z; sm[11]+=r2.w;
    }
    #pragma unroll
    for (int m = 1; m < 8; m <<= 1)
      #pragma unroll
      for (int w = 0; w < 12; ++w)
        sm[w] += __shfl_xor(sm[w], m, 64);
    if (part == 0){
      int bb = pr & 15, kk = pr >> 4;
      #pragma unroll
      for (int w = 0; w < 12; ++w)
        feats[bb*24 + kk*12 + w] = sm[w];
    }
  }
  __syncthreads();

  for (int e = tid; e < 2048; e += 256){
    int bb = e >> 7, j = e & 127;
    const float4* wr = (const float4*)(w1 + j*24);
    const float4* fr = (const float4*)(feats + bb*24);
    float s = b1[j];
    #pragma unroll
    for (int q = 0; q < 6; ++q){
      float4 a = fr[q], w4 = wr[q];
      s += a.x*w4.x + a.y*w4.y + a.z*w4.z + a.w*w4.w;
    }
    h1[e] = fmaxf(s, 0.f);
  }
  __syncthreads();
  for (int e = tid; e < 1024; e += 256){
    int bb = e >> 6, j = e & 63;
    const float4* wr = (const float4*)(w2 + j*128);
    const float4* hr = (const float4*)(h1 + bb*128);
    float s = b2[j];
    #pragma unroll
    for (int q = 0; q < 32; ++q){
      float4 a = hr[q], w4 = wr[q];
      s += a.x*w4.x + a.y*w4.y + a.z*w4.z + a.w*w4.w;
    }
    h2[e] = fmaxf(s, 0.f);
  }
  __syncthreads();
  if (tid < 64){
    int bb = tid >> 2, j = tid & 3;
    const float4* wr = (const float4*)(w3 + j*64);
    const float4* hr = (const float4*)(h2 + bb*64);
    float s = b3[j];
    #pragma unroll
    for (int q = 0; q < 16; ++q){
      float4 a = hr[q], w4 = wr[q];
      s += a.x*w4.x + a.y*w4.y + a.z*w4.z + a.w*w4.w;
    }
    out[tid] = s;
  }
}

extern "C" void kernel_launch(void* const* d_in, const int* in_sizes, int n_in,
                              void* d_out, int out_size, void* d_ws, size_t ws_size,
                              hipStream_t stream) {
  const float* x  = (const float*)d_in[0];
  const float* kp = (const float*)d_in[1];
  const float* w1 = (const float*)d_in[2];
  const float* b1 = (const float*)d_in[3];
  const float* w2 = (const float*)d_in[4];
  const float* b2 = (const float*)d_in[5];
  const float* w3 = (const float*)d_in[6];
  const float* b3 = (const float*)d_in[7];
  float* out = (float*)d_out;

  char* ws = (char*)d_ws;
  cplx*  psi_g = (cplx*)ws;                 // 32*1024*8 = 262144 B
  float* cs_g  = (float*)(ws + 262144);     // 32*32*4   = 4096 B
  float* pacc  = (float*)(ws + 266240);     // 2048*12*4 = 98304 B

  stage1_kernel<<<32, 64, 0, stream>>>(x, kp, psi_g, cs_g, 6);
  stage3_kernel<<<512, 256, 0, stream>>>(psi_g, cs_g, kp, pacc, 6);
  mlp_kernel<<<1, 256, 0, stream>>>(pacc, w1, b1, w2, b2, w3, b3, out);
}